// Round 12
// baseline (78.198 us; speedup 1.0000x reference)
//
#include <hip/hip_runtime.h>

// Segment attention pooling, MI355X (gfx950).
// convw_pack (fp32 W -> bf16, MFMA-fragment order) ; segscan ;
// score_gemm (whole A-tile LDS-resident, barrier-free K-loop, 16 waves,
// PER-WAVE K-PHASE STAGGER to break phase-lock) ; pool.

#define SEP_ID 102
#define Bn 64
#define Sn 512
#define Hn 768
#define Mn 21
#define BS (Bn * Sn)

typedef __attribute__((ext_vector_type(8))) short bf16x8;
typedef __attribute__((ext_vector_type(8))) unsigned short u16x8;
typedef __attribute__((ext_vector_type(4))) float f32x4;

__device__ inline unsigned short f2bf(float x) {
  unsigned int u = __builtin_bit_cast(unsigned int, x);
  u += 0x7fffu + ((u >> 16) & 1u);   // RNE
  return (unsigned short)(u >> 16);
}

__device__ inline u16x8 cvt8v(f32x4 a, f32x4 b) {
  u16x8 r;
  r[0] = f2bf(a[0]); r[1] = f2bf(a[1]); r[2] = f2bf(a[2]); r[3] = f2bf(a[3]);
  r[4] = f2bf(b[0]); r[5] = f2bf(b[1]); r[6] = f2bf(b[2]); r[7] = f2bf(b[3]);
  return r;
}

__device__ inline float tanh_fast(float x) {
  float e = __builtin_amdgcn_exp2f(x * 2.885390081777927f); // 2*log2(e)
  return 1.f - 2.f * __builtin_amdgcn_rcpf(e + 1.f);
}

// ---------------- kernel 1: W fp32 -> bf16, packed in MFMA B-fragment order.
// chunk c = (ntile*24 + kstep)*64 + lane; holds W[ntile*16 + (lane&15)]
// [kstep*32 + (lane>>4)*8 ..+8]  -> score_gemm B loads are lane-contiguous.
__global__ void convw_kernel(const float* __restrict__ W, unsigned short* __restrict__ WBp) {
  int c = blockIdx.x * 256 + threadIdx.x;   // 73728 chunks, grid 288
  int nt = c / 1536;
  int r  = c % 1536;
  int ks = r >> 6;
  int ln = r & 63;
  int col = nt * 16 + (ln & 15);
  int k0  = ks * 32 + (ln >> 4) * 8;
  const f32x4* src = reinterpret_cast<const f32x4*>(&W[col * Hn + k0]);
  f32x4 a = src[0];
  f32x4 b = src[1];
  *reinterpret_cast<u16x8*>(&WBp[(size_t)c * 8]) = cvt8v(a, b);
}

// ---------------- kernel 2: per-batch segment scan
__global__ void segscan_kernel(const int* __restrict__ ids,
                               unsigned char* __restrict__ segv,
                               int* __restrict__ nsep) {
  int b = blockIdx.x;
  int s = threadIdx.x;
  __shared__ int cs[Sn];
  int sep = (ids[b * Sn + s] == SEP_ID) ? 1 : 0;
  cs[s] = sep;
  __syncthreads();
  for (int off = 1; off < Sn; off <<= 1) {
    int add = (s >= off) ? cs[s - off] : 0;
    __syncthreads();
    cs[s] += add;
    __syncthreads();
  }
  int csum = cs[s];
  int nb = cs[Sn - 1];
  int seg = csum - sep;
  bool valid = (!sep) && (s >= 1) && (seg < nb) && (seg < Mn);
  segv[b * Sn + s] = valid ? (unsigned char)seg : (unsigned char)0xFF;
  if (s == 0) nsep[b] = nb;
}

// ---------------- kernel 3: scores = v . tanh(hidden @ W^T + b)
// 1024 thr = 16 waves, block = 64 rows x 768 cols, wave = 64 rows x 48 cols.
// Prologue: stage whole 64x768 A-tile (fp32->bf16) into LDS, one barrier.
// K-loop: 24 steps, NO barriers. Each wave starts its K-ring at a different
// offset (woff = (wid&7)*3) and walks all 24 steps mod 24 -- waves occupy 8
// distinct phases, so one wave's loads overlap another's MFMAs (breaks the
// phase-lock that serialized the pipes at ~21% each). K-sum order-independent.
__global__ __launch_bounds__(1024, 4) void score_gemm_kernel(
    const float* __restrict__ hid, const unsigned short* __restrict__ WBp,
    const float* __restrict__ bbias, const float* __restrict__ vvec,
    float* __restrict__ scores) {
  __shared__ __align__(16) unsigned short As[64 * 768];   // 98304 B
  __shared__ float scpart[16][64];

  const int t = threadIdx.x;
  const size_t rowBase = (size_t)blockIdx.x * 64;
  const int wid = t >> 6, lane = t & 63;
  const int l15 = lane & 15, l4 = lane >> 4;
  const int colBase = wid * 48;

  // ---- prologue: stage A (row = t>>4, 16B chunk scloc = t&15, one chunk per
  // each of the 6 K-chunks of 128). XOR-swizzle chunk ^ (row&7).
  {
    const int srow = t >> 4;
    const int scloc = t & 15;
    const f32x4* hsrc = reinterpret_cast<const f32x4*>(
        &hid[(rowBase + srow) * Hn + scloc * 8]);   // f32x4 units
    unsigned short* const arow = &As[srow * Hn];
    const int swz = srow & 7;
    f32x4 p[6][2];
#pragma unroll
    for (int cc = 0; cc < 6; ++cc) {
      p[cc][0] = hsrc[cc * 32];
      p[cc][1] = hsrc[cc * 32 + 1];
    }
#pragma unroll
    for (int cc = 0; cc < 6; ++cc)
      *reinterpret_cast<u16x8*>(arow + ((cc * 16 + scloc) ^ swz) * 8) =
          cvt8v(p[cc][0], p[cc][1]);
  }
  __syncthreads();

  // A frag read base: row = mi*16 + l15, chunk = (kk*4 + l4) ^ (l15&7)
  const unsigned short* const afrow = &As[l15 * Hn];
  const int aswz = l15 & 7;
  // B: packed fragment chunks, ntile = wid*3 + ni, per-kstep stride 512 shorts
  const unsigned short* bp0 = &WBp[((size_t)(wid * 3 + 0) * 24 * 64 + lane) * 8];
  const unsigned short* bp1 = &WBp[((size_t)(wid * 3 + 1) * 24 * 64 + lane) * 8];
  const unsigned short* bp2 = &WBp[((size_t)(wid * 3 + 2) * 24 * 64 + lane) * 8];

  f32x4 acc[4][3];
#pragma unroll
  for (int mi = 0; mi < 4; ++mi)
#pragma unroll
    for (int ni = 0; ni < 3; ++ni) acc[mi][ni] = (f32x4){0.f, 0.f, 0.f, 0.f};

  // per-wave K-ring start (8 phases across 16 waves)
  const int woff = (wid & 7) * 3;
  int kkv = woff;

  // double buffers: afA/afB (A frags), brA/brB (B frags)
  bf16x8 afA[4], afB[4], brA[3], brB[3];
#pragma unroll
  for (int mi = 0; mi < 4; ++mi)
    afA[mi] = *reinterpret_cast<const bf16x8*>(
        &afrow[mi * 16 * Hn + (((kkv * 4 + l4) ^ aswz)) * 8]);
  brA[0] = *reinterpret_cast<const bf16x8*>(bp0 + kkv * 512);
  brA[1] = *reinterpret_cast<const bf16x8*>(bp1 + kkv * 512);
  brA[2] = *reinterpret_cast<const bf16x8*>(bp2 + kkv * 512);

  // one pipeline step: load ring-next into afn/brn, then MFMA on afc/brc
#define STEP(k2_, afc, afn, brc, brn)                                       \
  {                                                                         \
    const int kn = (kkv == 23) ? 0 : (kkv + 1);                             \
    if ((k2_) < 23) {                                                       \
      _Pragma("unroll")                                                     \
      for (int mi = 0; mi < 4; ++mi)                                        \
        afn[mi] = *reinterpret_cast<const bf16x8*>(                         \
            &afrow[mi * 16 * Hn + (((kn * 4 + l4) ^ aswz)) * 8]);           \
      brn[0] = *reinterpret_cast<const bf16x8*>(bp0 + kn * 512);            \
      brn[1] = *reinterpret_cast<const bf16x8*>(bp1 + kn * 512);            \
      brn[2] = *reinterpret_cast<const bf16x8*>(bp2 + kn * 512);            \
    }                                                                       \
    __builtin_amdgcn_sched_barrier(0);                                      \
    _Pragma("unroll")                                                       \
    for (int mi = 0; mi < 4; ++mi)                                          \
      _Pragma("unroll")                                                     \
      for (int ni = 0; ni < 3; ++ni)                                        \
        acc[mi][ni] = __builtin_amdgcn_mfma_f32_16x16x32_bf16(              \
            afc[mi], brc[ni], acc[mi][ni], 0, 0, 0);                        \
    kkv = kn;                                                               \
  }

#pragma unroll
  for (int k2 = 0; k2 < 12; ++k2) {
    STEP(k2 * 2,     afA, afB, brA, brB)
    STEP(k2 * 2 + 1, afB, afA, brB, brA)
  }
#undef STEP

  // ---- fused epilogue: tanh(pre + b) * v over the wave's 48 cols
  float sc[4][4];
#pragma unroll
  for (int mi = 0; mi < 4; ++mi)
#pragma unroll
    for (int r = 0; r < 4; ++r) sc[mi][r] = 0.f;
#pragma unroll
  for (int ni = 0; ni < 3; ++ni) {
    int col = colBase + ni * 16 + l15;
    float vv = vvec[col];
    float bb = bbias[col];
#pragma unroll
    for (int mi = 0; mi < 4; ++mi)
#pragma unroll
      for (int r = 0; r < 4; ++r)
        sc[mi][r] += tanh_fast(acc[mi][ni][r] + bb) * vv;
  }
#pragma unroll
  for (int off = 1; off < 16; off <<= 1)
#pragma unroll
    for (int mi = 0; mi < 4; ++mi)
#pragma unroll
      for (int r = 0; r < 4; ++r)
        sc[mi][r] += __shfl_xor(sc[mi][r], off, 64);
  if (l15 == 0) {
#pragma unroll
    for (int mi = 0; mi < 4; ++mi)
#pragma unroll
      for (int r = 0; r < 4; ++r)
        scpart[wid][mi * 16 + l4 * 4 + r] = sc[mi][r];
  }
  __syncthreads();
  if (t < 64) {
    float s = 0.f;
#pragma unroll
    for (int w = 0; w < 16; ++w) s += scpart[w][t];
    scores[rowBase + t] = s;
  }
}

// ---------------- kernel 4: per-(b,m) segment softmax + pooling
__global__ __launch_bounds__(256) void pool_kernel(
    const float* __restrict__ hid, const float* __restrict__ scores,
    const unsigned char* __restrict__ segv, const int* __restrict__ nsep,
    float* __restrict__ out) {
  int bm = blockIdx.x;
  int b = bm / Mn, m = bm % Mn;
  int t = threadIdx.x;
  __shared__ float wLds[Sn];
  __shared__ float red[256];
  __shared__ int ired[256];
  const float NEG = -1e30f;

  int base = b * Sn;
  unsigned char mg = (unsigned char)m;
  unsigned char g0 = segv[base + t], g1 = segv[base + 256 + t];
  bool v0 = (g0 == mg), v1 = (g1 == mg);
  float s0 = v0 ? scores[base + t] : NEG;
  float s1 = v1 ? scores[base + 256 + t] : NEG;

  red[t] = fmaxf(s0, s1);
  __syncthreads();
  for (int o = 128; o > 0; o >>= 1) {
    if (t < o) red[t] = fmaxf(red[t], red[t + o]);
    __syncthreads();
  }
  float gmax = red[0];
  __syncthreads();

  size_t obase = (size_t)bm * Hn;
  if (gmax <= -0.5e30f) {
    int nb = nsep[b];
    float a0 = 0.f, a1 = 0.f, a2 = 0.f;
    if (m == 0 && nb == 0) {
      const float* hp = hid + (size_t)base * Hn;
      a0 = hp[t]; a1 = hp[t + 256]; a2 = hp[t + 512];
    }
    out[obase + t] = a0; out[obase + 256 + t] = a1; out[obase + 512 + t] = a2;
    return;
  }

  float e0 = v0 ? expf(s0 - gmax) : 0.f;
  float e1 = v1 ? expf(s1 - gmax) : 0.f;
  red[t] = e0 + e1;
  __syncthreads();
  for (int o = 128; o > 0; o >>= 1) {
    if (t < o) red[t] += red[t + o];
    __syncthreads();
  }
  float inv = 1.f / red[0];
  __syncthreads();
  wLds[t] = e0 * inv;
  wLds[256 + t] = e1 * inv;

  ired[t] = min(v0 ? t : 0x7fffffff, v1 ? (256 + t) : 0x7fffffff);
  __syncthreads();
  for (int o = 128; o > 0; o >>= 1) {
    if (t < o) ired[t] = min(ired[t], ired[t + o]);
    __syncthreads();
  }
  int start = ired[0];
  __syncthreads();
  ired[t] = max(v0 ? t : -1, v1 ? (256 + t) : -1);
  __syncthreads();
  for (int o = 128; o > 0; o >>= 1) {
    if (t < o) ired[t] = max(ired[t], ired[t + o]);
    __syncthreads();
  }
  int end = ired[0];
  __syncthreads();

  float a0 = 0.f, a1 = 0.f, a2 = 0.f;
  for (int s = start; s <= end; ++s) {
    float w = wLds[s];
    if (w != 0.f) {
      const float* hp = hid + (size_t)(base + s) * Hn;
      a0 += w * hp[t];
      a1 += w * hp[t + 256];
      a2 += w * hp[t + 512];
    }
  }
  out[obase + t] = a0;
  out[obase + 256 + t] = a1;
  out[obase + 512 + t] = a2;
}

// ---------------- launch
extern "C" void kernel_launch(void* const* d_in, const int* in_sizes, int n_in,
                              void* d_out, int out_size, void* d_ws, size_t ws_size,
                              hipStream_t stream) {
  const float* hidden = (const float*)d_in[0];
  const int* ids      = (const int*)d_in[1];
  const float* W      = (const float*)d_in[2];
  const float* bbias  = (const float*)d_in[3];
  const float* vvec   = (const float*)d_in[4];

  char* ws = (char*)d_ws;
  unsigned short* WBp  = (unsigned short*)(ws);            // 1,179,648 B
  float* scores        = (float*)(ws + 1179648);
  unsigned char* segv  = (unsigned char*)(ws + 1310720);
  int* nsep            = (int*)(ws + 1343488);

  convw_kernel<<<288, 256, 0, stream>>>(W, WBp);
  segscan_kernel<<<Bn, Sn, 0, stream>>>(ids, segv, nsep);
  score_gemm_kernel<<<BS / 64, 1024, 0, stream>>>(hidden, WBp, bbias, vvec, scores);
  pool_kernel<<<Bn * Mn, 256, 0, stream>>>(hidden, scores, segv, nsep, (float*)d_out);
}

// Round 13
// 75.602 us; speedup vs baseline: 1.0343x; 1.0343x over previous
//
#include <hip/hip_runtime.h>

// Segment attention pooling, MI355X (gfx950).
// convw_pack (fp32 W -> bf16, MFMA-fragment order) ; segscan ;
// score_gemm (whole A-tile LDS-resident, barrier-free K-loop,
// 8 FAT waves (64x96, 256-reg budget), A-frag dbuf + depth-2 B ring) ; pool.

#define SEP_ID 102
#define Bn 64
#define Sn 512
#define Hn 768
#define Mn 21
#define BS (Bn * Sn)

typedef __attribute__((ext_vector_type(8))) short bf16x8;
typedef __attribute__((ext_vector_type(8))) unsigned short u16x8;
typedef __attribute__((ext_vector_type(4))) float f32x4;

__device__ inline unsigned short f2bf(float x) {
  unsigned int u = __builtin_bit_cast(unsigned int, x);
  u += 0x7fffu + ((u >> 16) & 1u);   // RNE
  return (unsigned short)(u >> 16);
}

__device__ inline u16x8 cvt8v(f32x4 a, f32x4 b) {
  u16x8 r;
  r[0] = f2bf(a[0]); r[1] = f2bf(a[1]); r[2] = f2bf(a[2]); r[3] = f2bf(a[3]);
  r[4] = f2bf(b[0]); r[5] = f2bf(b[1]); r[6] = f2bf(b[2]); r[7] = f2bf(b[3]);
  return r;
}

__device__ inline float tanh_fast(float x) {
  float e = __builtin_amdgcn_exp2f(x * 2.885390081777927f); // 2*log2(e)
  return 1.f - 2.f * __builtin_amdgcn_rcpf(e + 1.f);
}

// ---------------- kernel 1: W fp32 -> bf16, packed in MFMA B-fragment order.
// chunk c = (ntile*24 + kstep)*64 + lane; holds W[ntile*16 + (lane&15)]
// [kstep*32 + (lane>>4)*8 ..+8]  -> score_gemm B loads are lane-contiguous.
__global__ void convw_kernel(const float* __restrict__ W, unsigned short* __restrict__ WBp) {
  int c = blockIdx.x * 256 + threadIdx.x;   // 73728 chunks, grid 288
  int nt = c / 1536;
  int r  = c % 1536;
  int ks = r >> 6;
  int ln = r & 63;
  int col = nt * 16 + (ln & 15);
  int k0  = ks * 32 + (ln >> 4) * 8;
  const f32x4* src = reinterpret_cast<const f32x4*>(&W[col * Hn + k0]);
  f32x4 a = src[0];
  f32x4 b = src[1];
  *reinterpret_cast<u16x8*>(&WBp[(size_t)c * 8]) = cvt8v(a, b);
}

// ---------------- kernel 2: per-batch segment scan
__global__ void segscan_kernel(const int* __restrict__ ids,
                               unsigned char* __restrict__ segv,
                               int* __restrict__ nsep) {
  int b = blockIdx.x;
  int s = threadIdx.x;
  __shared__ int cs[Sn];
  int sep = (ids[b * Sn + s] == SEP_ID) ? 1 : 0;
  cs[s] = sep;
  __syncthreads();
  for (int off = 1; off < Sn; off <<= 1) {
    int add = (s >= off) ? cs[s - off] : 0;
    __syncthreads();
    cs[s] += add;
    __syncthreads();
  }
  int csum = cs[s];
  int nb = cs[Sn - 1];
  int seg = csum - sep;
  bool valid = (!sep) && (s >= 1) && (seg < nb) && (seg < Mn);
  segv[b * Sn + s] = valid ? (unsigned char)seg : (unsigned char)0xFF;
  if (s == 0) nsep[b] = nb;
}

// ---------------- kernel 3: scores = v . tanh(hidden @ W^T + b)
// 512 thr = 8 waves, block = 64 rows x 768 cols, wave = 64 rows x 96 cols.
// __launch_bounds__(512,2) -> 256 regs/wave: acc 96 AGPR + A dbuf 32 +
// depth-2 B ring 96 VGPR fit WITHOUT spilling (the 16-wave variants were
// capped at 128 and every deeper-prefetch attempt spilled or collapsed).
// Prologue: stage whole 64x768 A-tile (fp32->bf16) into LDS, one barrier.
// K-loop: 24 steps, NO barriers (A read-only; waves free-run).
__global__ __launch_bounds__(512, 2) void score_gemm_kernel(
    const float* __restrict__ hid, const unsigned short* __restrict__ WBp,
    const float* __restrict__ bbias, const float* __restrict__ vvec,
    float* __restrict__ scores) {
  __shared__ __align__(16) unsigned short As[64 * 768];   // 98304 B
  __shared__ float scpart[8][64];

  const int t = threadIdx.x;
  const size_t rowBase = (size_t)blockIdx.x * 64;
  const int wid = t >> 6, lane = t & 63;
  const int l15 = lane & 15, l4 = lane >> 4;
  const int colBase = wid * 96;

  // ---- prologue: stage A. Thread t: row = t>>3, chunk set c = (t&7) + 8j,
  // j = 0..11 (96 chunks of 16B per row). XOR-swizzle chunk ^ (row&7) stays
  // within each aligned-8 chunk group: (sq+8j)^swz = (sq^swz)+8j.
  {
    const int srow = t >> 3;
    const int sq = t & 7;
    const f32x4* hsrc = reinterpret_cast<const f32x4*>(
        &hid[(rowBase + srow) * Hn + sq * 8]);      // f32x4 units, +2 per chunk
    unsigned short* const arow = &As[srow * Hn];
    const int wq = (sq ^ (srow & 7));
    f32x4 p[12][2];
#pragma unroll
    for (int j = 0; j < 12; ++j) {
      p[j][0] = hsrc[j * 16];
      p[j][1] = hsrc[j * 16 + 1];
    }
#pragma unroll
    for (int j = 0; j < 12; ++j)
      *reinterpret_cast<u16x8*>(arow + (wq + 8 * j) * 8) = cvt8v(p[j][0], p[j][1]);
  }
  __syncthreads();

  // A frag read base: row = mi*16 + l15, chunk = (kk*4 + l4) ^ (l15&7)
  const unsigned short* const afrow = &As[l15 * Hn];
  const int aswz = l15 & 7;
  // B: packed fragment chunks, ntile = wid*6 + ni, per-kstep stride 512 shorts
  const unsigned short* bp[6];
#pragma unroll
  for (int ni = 0; ni < 6; ++ni)
    bp[ni] = &WBp[((size_t)(wid * 6 + ni) * 24 * 64 + lane) * 8];

  f32x4 acc[4][6];
#pragma unroll
  for (int mi = 0; mi < 4; ++mi)
#pragma unroll
    for (int ni = 0; ni < 6; ++ni) acc[mi][ni] = (f32x4){0.f, 0.f, 0.f, 0.f};

  // double buffers: afA/afB (A frags), brA/brB (B frags, 6 each)
  bf16x8 afA[4], afB[4], brA[6], brB[6];
#pragma unroll
  for (int mi = 0; mi < 4; ++mi)
    afA[mi] = *reinterpret_cast<const bf16x8*>(
        &afrow[mi * 16 * Hn + ((l4 ^ aswz)) * 8]);          // kk = 0
#pragma unroll
  for (int ni = 0; ni < 6; ++ni)
    brA[ni] = *reinterpret_cast<const bf16x8*>(bp[ni]);

  // one pipeline step: load (kk+1) into afn/brn, then 24 MFMA on afc/brc
#define STEP(kk_, afc, afn, brc, brn)                                       \
  {                                                                         \
    if ((kk_) < 23) {                                                       \
      _Pragma("unroll")                                                     \
      for (int mi = 0; mi < 4; ++mi)                                        \
        afn[mi] = *reinterpret_cast<const bf16x8*>(                         \
            &afrow[mi * 16 * Hn + ((((kk_) + 1) * 4 + l4) ^ aswz) * 8]);    \
      _Pragma("unroll")                                                     \
      for (int ni = 0; ni < 6; ++ni)                                        \
        brn[ni] = *reinterpret_cast<const bf16x8*>(bp[ni] + ((kk_) + 1) * 512); \
    }                                                                       \
    __builtin_amdgcn_sched_barrier(0);                                      \
    _Pragma("unroll")                                                       \
    for (int mi = 0; mi < 4; ++mi)                                          \
      _Pragma("unroll")                                                     \
      for (int ni = 0; ni < 6; ++ni)                                        \
        acc[mi][ni] = __builtin_amdgcn_mfma_f32_16x16x32_bf16(              \
            afc[mi], brc[ni], acc[mi][ni], 0, 0, 0);                        \
  }

#pragma unroll
  for (int k2 = 0; k2 < 12; ++k2) {
    STEP(k2 * 2,     afA, afB, brA, brB)
    STEP(k2 * 2 + 1, afB, afA, brB, brA)
  }
#undef STEP

  // ---- fused epilogue: tanh(pre + b) * v over the wave's 96 cols
  float sc[4][4];
#pragma unroll
  for (int mi = 0; mi < 4; ++mi)
#pragma unroll
    for (int r = 0; r < 4; ++r) sc[mi][r] = 0.f;
#pragma unroll
  for (int ni = 0; ni < 6; ++ni) {
    int col = colBase + ni * 16 + l15;
    float vv = vvec[col];
    float bb = bbias[col];
#pragma unroll
    for (int mi = 0; mi < 4; ++mi)
#pragma unroll
      for (int r = 0; r < 4; ++r)
        sc[mi][r] += tanh_fast(acc[mi][ni][r] + bb) * vv;
  }
#pragma unroll
  for (int off = 1; off < 16; off <<= 1)
#pragma unroll
    for (int mi = 0; mi < 4; ++mi)
#pragma unroll
      for (int r = 0; r < 4; ++r)
        sc[mi][r] += __shfl_xor(sc[mi][r], off, 64);
  if (l15 == 0) {
#pragma unroll
    for (int mi = 0; mi < 4; ++mi)
#pragma unroll
      for (int r = 0; r < 4; ++r)
        scpart[wid][mi * 16 + l4 * 4 + r] = sc[mi][r];
  }
  __syncthreads();
  if (t < 64) {
    float s = 0.f;
#pragma unroll
    for (int w = 0; w < 8; ++w) s += scpart[w][t];
    scores[rowBase + t] = s;
  }
}

// ---------------- kernel 4: per-(b,m) segment softmax + pooling
__global__ __launch_bounds__(256) void pool_kernel(
    const float* __restrict__ hid, const float* __restrict__ scores,
    const unsigned char* __restrict__ segv, const int* __restrict__ nsep,
    float* __restrict__ out) {
  int bm = blockIdx.x;
  int b = bm / Mn, m = bm % Mn;
  int t = threadIdx.x;
  __shared__ float wLds[Sn];
  __shared__ float red[256];
  __shared__ int ired[256];
  const float NEG = -1e30f;

  int base = b * Sn;
  unsigned char mg = (unsigned char)m;
  unsigned char g0 = segv[base + t], g1 = segv[base + 256 + t];
  bool v0 = (g0 == mg), v1 = (g1 == mg);
  float s0 = v0 ? scores[base + t] : NEG;
  float s1 = v1 ? scores[base + 256 + t] : NEG;

  red[t] = fmaxf(s0, s1);
  __syncthreads();
  for (int o = 128; o > 0; o >>= 1) {
    if (t < o) red[t] = fmaxf(red[t], red[t + o]);
    __syncthreads();
  }
  float gmax = red[0];
  __syncthreads();

  size_t obase = (size_t)bm * Hn;
  if (gmax <= -0.5e30f) {
    int nb = nsep[b];
    float a0 = 0.f, a1 = 0.f, a2 = 0.f;
    if (m == 0 && nb == 0) {
      const float* hp = hid + (size_t)base * Hn;
      a0 = hp[t]; a1 = hp[t + 256]; a2 = hp[t + 512];
    }
    out[obase + t] = a0; out[obase + 256 + t] = a1; out[obase + 512 + t] = a2;
    return;
  }

  float e0 = v0 ? expf(s0 - gmax) : 0.f;
  float e1 = v1 ? expf(s1 - gmax) : 0.f;
  red[t] = e0 + e1;
  __syncthreads();
  for (int o = 128; o > 0; o >>= 1) {
    if (t < o) red[t] += red[t + o];
    __syncthreads();
  }
  float inv = 1.f / red[0];
  __syncthreads();
  wLds[t] = e0 * inv;
  wLds[256 + t] = e1 * inv;

  ired[t] = min(v0 ? t : 0x7fffffff, v1 ? (256 + t) : 0x7fffffff);
  __syncthreads();
  for (int o = 128; o > 0; o >>= 1) {
    if (t < o) ired[t] = min(ired[t], ired[t + o]);
    __syncthreads();
  }
  int start = ired[0];
  __syncthreads();
  ired[t] = max(v0 ? t : -1, v1 ? (256 + t) : -1);
  __syncthreads();
  for (int o = 128; o > 0; o >>= 1) {
    if (t < o) ired[t] = max(ired[t], ired[t + o]);
    __syncthreads();
  }
  int end = ired[0];
  __syncthreads();

  float a0 = 0.f, a1 = 0.f, a2 = 0.f;
  for (int s = start; s <= end; ++s) {
    float w = wLds[s];
    if (w != 0.f) {
      const float* hp = hid + (size_t)(base + s) * Hn;
      a0 += w * hp[t];
      a1 += w * hp[t + 256];
      a2 += w * hp[t + 512];
    }
  }
  out[obase + t] = a0;
  out[obase + 256 + t] = a1;
  out[obase + 512 + t] = a2;
}

// ---------------- launch
extern "C" void kernel_launch(void* const* d_in, const int* in_sizes, int n_in,
                              void* d_out, int out_size, void* d_ws, size_t ws_size,
                              hipStream_t stream) {
  const float* hidden = (const float*)d_in[0];
  const int* ids      = (const int*)d_in[1];
  const float* W      = (const float*)d_in[2];
  const float* bbias  = (const float*)d_in[3];
  const float* vvec   = (const float*)d_in[4];

  char* ws = (char*)d_ws;
  unsigned short* WBp  = (unsigned short*)(ws);            // 1,179,648 B
  float* scores        = (float*)(ws + 1179648);
  unsigned char* segv  = (unsigned char*)(ws + 1310720);
  int* nsep            = (int*)(ws + 1343488);

  convw_kernel<<<288, 256, 0, stream>>>(W, WBp);
  segscan_kernel<<<Bn, Sn, 0, stream>>>(ids, segv, nsep);
  score_gemm_kernel<<<BS / 64, 512, 0, stream>>>(hidden, WBp, bbias, vvec, scores);
  pool_kernel<<<Bn * Mn, 256, 0, stream>>>(hidden, scores, segv, nsep, (float*)d_out);
}